// Round 1
// baseline (790.644 us; speedup 1.0000x reference)
//
#include <hip/hip_runtime.h>
#include <stdint.h>

typedef _Float16 f16;
typedef __attribute__((ext_vector_type(8))) _Float16 f16x8;
typedef __attribute__((ext_vector_type(4))) float f32x4;

#define MFMA(a, b, c) __builtin_amdgcn_mfma_f32_16x16x32_f16((a), (b), (c), 0, 0, 0)

static constexpr int C = 192;     // channels
// Algebraic folding (softmax is row-shift-invariant):
//   S = softmax(x^T M x + v[m]),  M = Wq^T Wk (192x192), v = (Wk^T qb)^T x
//   out = Wo (x P^T) + b2 + x,    Wo = Wp Wv, b2 = Wp vb + pb
// t = M' x  with M' rows 0..191 = M, row 192 = Wk^T qb (gives v), rows 193.. = 0
// t packed layout: [win][c4 (49)][tok (256)][4] f16 ; xh: [win][c][tok] f16

union U8x { uint2 u2[2]; f16x8 v; };

// ---------------- kernel 0: fold weights ----------------
// Mh[256][192] f16: rows 0..191 = Wq^T Wk ; row 192 = Wk^T qb ; rows 193..255 = 0
// Wo[192][192] f16: Wp @ Wv ;  b2[192] f32: Wp @ vb + pb
__global__ __launch_bounds__(256)
void prep_kernel(const float* __restrict__ qkv_w, const float* __restrict__ qkv_b,
                 const float* __restrict__ proj_w, const float* __restrict__ proj_b,
                 f16* __restrict__ Mh, f16* __restrict__ Wo, float* __restrict__ b2) {
    const int idx = blockIdx.x * 256 + threadIdx.x;
    if (idx < 256 * 192) {
        const int r = idx / 192, c = idx % 192;
        float s = 0.f;
        if (r < 192) {
#pragma unroll 4
            for (int o = 0; o < 192; ++o)
                s += qkv_w[o * 192 + r] * qkv_w[(192 + o) * 192 + c];   // Wq[o,r]*Wk[o,c]
        } else if (r == 192) {
#pragma unroll 4
            for (int o = 0; o < 192; ++o)
                s += qkv_b[o] * qkv_w[(192 + o) * 192 + c];             // qb[o]*Wk[o,c]
        }
        Mh[idx] = (f16)s;
    } else if (idx < 256 * 192 + 192 * 192) {
        const int j = idx - 256 * 192;
        const int r = j / 192, c = j % 192;
        float s = 0.f;
#pragma unroll 4
        for (int c2 = 0; c2 < 192; ++c2)
            s += proj_w[r * 192 + c2] * qkv_w[(384 + c2) * 192 + c];    // Wp[r,c2]*Wv[c2,c]
        Wo[j] = (f16)s;
    } else if (idx < 256 * 192 + 192 * 192 + 192) {
        const int o = idx - (256 * 192 + 192 * 192);
        float s = proj_b[o];
        for (int c2 = 0; c2 < 192; ++c2)
            s += proj_w[o * 192 + c2] * qkv_b[384 + c2];                // Wp[o,c2]*vb[c2]
        b2[o] = s;
    }
}

// ---------------- kernel 1: t = M' x  (+ f16 passthrough of x) ----------------
// grid: 4096 = 1024 windows * 4 token-blocks ; block: 256 threads (4 waves)
#define XS 200  // LDS row stride (f16): 16B-aligned rows
__global__ __launch_bounds__(256, 4)
void xt_kernel(const float* __restrict__ x, const f16* __restrict__ Mh,
               f16* __restrict__ tpk, f16* __restrict__ xh) {
    __shared__ f16 xs[64 * XS];  // [token_local][c]
    const int tid = threadIdx.x;
    const int wg = blockIdx.x;
    const int win = wg >> 2, tb = wg & 3;
    const int batch = win >> 8, wh = (win >> 4) & 15, ww = win & 15;
    const int i0 = tb * 4;  // first window-row of this 64-token block

    // stage x tile -> xs[token][c] (f16), coalesced float4 reads
    for (int e = 0; e < 12; ++e) {
        int f = e * 1024 + tid * 4;      // covers c*64 + nl, 12288 elements
        int c = f >> 6, nl = f & 63;
        int i = nl >> 4, j = nl & 15;    // j in {0,4,8,12}
        const float4 v4 = *(const float4*)(x + (((size_t)(batch * C + c) * 256 + (wh * 16 + i0 + i)) * 256 + ww * 16 + j));
        xs[(nl + 0) * XS + c] = (f16)v4.x;
        xs[(nl + 1) * XS + c] = (f16)v4.y;
        xs[(nl + 2) * XS + c] = (f16)v4.z;
        xs[(nl + 3) * XS + c] = (f16)v4.w;
    }
    __syncthreads();

    const int wave = tid >> 6, lane = tid & 63, l15 = lane & 15, qd = lane >> 4;
    // wave w owns 64 output rows [64w, 64w+64) of t (208 real rows; rest zero-padded)
    const int rb = wave;
    const int nmi = (wave == 3) ? 1 : 4;   // wave 3 only needs rows 192..207
    f32x4 acc[4][4] = {};  // [mi][ti]
#pragma unroll
    for (int k = 0; k < 6; ++k) {
        const int c0 = k * 32 + qd * 8;
        f16x8 af[4], bf[4];
#pragma unroll
        for (int mi = 0; mi < 4; ++mi)
            if (mi < nmi)
                af[mi] = *(const f16x8*)(Mh + (rb * 64 + mi * 16 + l15) * C + c0);
#pragma unroll
        for (int ti = 0; ti < 4; ++ti)
            bf[ti] = *(const f16x8*)(xs + (ti * 16 + l15) * XS + c0);
#pragma unroll
        for (int mi = 0; mi < 4; ++mi)
            if (mi < nmi)
#pragma unroll
                for (int ti = 0; ti < 4; ++ti)
                    acc[mi][ti] = MFMA(af[mi], bf[ti], acc[mi][ti]);
    }
    // epilogue: packed-c4 stores (coalesced 8B), rows 4-aligned per qd
#pragma unroll
    for (int mi = 0; mi < 4; ++mi) {
        if (mi >= nmi) continue;
        const int c4 = rb * 16 + mi * 4 + qd;
        if (c4 < 49) {
#pragma unroll
            for (int ti = 0; ti < 4; ++ti) {
                const int tok = tb * 64 + ti * 16 + l15;
                union { f16 h[4]; uint2 u; } pk;
                pk.h[0] = (f16)acc[mi][ti][0];
                pk.h[1] = (f16)acc[mi][ti][1];
                pk.h[2] = (f16)acc[mi][ti][2];
                pk.h[3] = (f16)acc[mi][ti][3];
                *(uint2*)(tpk + (((size_t)win * 49 + c4) * 256 + tok) * 4) = pk.u;
            }
        }
    }
    // f16 passthrough of x, channel-major [win][c][tok] (coalesced 8B stores)
    for (int it = 0; it < 12; ++it) {
        int e = it * 256 + tid;          // 3072 = 192 c * 16 tok-groups
        int c = e >> 4, t4 = (e & 15) * 4;
        union { f16 h[4]; uint2 u; } pk;
        pk.h[0] = xs[(t4 + 0) * XS + c];
        pk.h[1] = xs[(t4 + 1) * XS + c];
        pk.h[2] = xs[(t4 + 2) * XS + c];
        pk.h[3] = xs[(t4 + 3) * XS + c];
        *(uint2*)(xh + ((size_t)win * C + c) * 256 + tb * 64 + t4) = pk.u;
    }
}

// ---------------- kernel 2: fused attention + proj + residual ----------------
// grid: 4096 ; block: 256 threads (4 waves). XCD swizzle: 4 WGs of one window -> same XCD.
#define SQS 200  // sQ / sOT row stride (f16)
#define SPS 72   // sP row stride (f16), holds one 64-col chunk
__global__ __launch_bounds__(256, 4)
void attn_kernel(const float* __restrict__ x, const f16* __restrict__ tpk,
                 const f16* __restrict__ xh, const f16* __restrict__ Wo,
                 const float* __restrict__ b2, float* __restrict__ out) {
    __shared__ f16 sQ[64 * SQS];   // x rows [n][c]; later reused as sOT [n][c]
    __shared__ f16 sP[64 * SPS];   // softmaxed scores, one 64-col chunk
    __shared__ float sRed[4][64];
    __shared__ float sMax[64];
    __shared__ float sSum[64];

    const int tid = threadIdx.x;
    const int wg = blockIdx.x;
    const int win = ((wg >> 5) << 3) | (wg & 7);
    const int rblk = (wg >> 3) & 3;
    const int batch = win >> 8, wh = (win >> 4) & 15, ww = win & 15;
    const int wave = tid >> 6, lane = tid & 63, l15 = lane & 15, qd = lane >> 4;

    // stage this rblk's 64 x-rows -> sQ[n][c] (f16), directly from x (fp32)
    for (int e = 0; e < 12; ++e) {
        int f = e * 1024 + tid * 4;
        int c = f >> 6, nl = f & 63;
        int i = nl >> 4, j = nl & 15;
        const float4 v4 = *(const float4*)(x + (((size_t)(batch * C + c) * 256 + (wh * 16 + rblk * 4 + i)) * 256 + ww * 16 + j));
        sQ[(nl + 0) * SQS + c] = (f16)v4.x;
        sQ[(nl + 1) * SQS + c] = (f16)v4.y;
        sQ[(nl + 2) * SQS + c] = (f16)v4.z;
        sQ[(nl + 3) * SQS + c] = (f16)v4.w;
    }
    // v[m] offsets (row 192 of t, c4=48 comp 0) — issue loads early
    float vm[4];
#pragma unroll
    for (int ti = 0; ti < 4; ++ti)
        vm[ti] = (float)tpk[(((size_t)win * 49 + 48) * 256 + wave * 64 + ti * 16 + l15) * 4];
    __syncthreads();

    // ---- phase S: A[n][m] = x^T t ; wave -> 64-col block
    f32x4 accS[4][4] = {};  // [mi: row subtile][ti: col subtile]
#pragma unroll
    for (int k = 0; k < 6; ++k) {
        const int c0 = k * 32 + qd * 8;
        const int c4 = c0 >> 2;
        f16x8 af[4], bf[4];
#pragma unroll
        for (int mi = 0; mi < 4; ++mi)
            af[mi] = *(const f16x8*)(sQ + (mi * 16 + l15) * SQS + c0);
#pragma unroll
        for (int ti = 0; ti < 4; ++ti) {
            const int m = wave * 64 + ti * 16 + l15;
            const size_t a = (((size_t)win * 49 + c4) * 256 + m) * 4;
            U8x b;
            b.u2[0] = *(const uint2*)(tpk + a);
            b.u2[1] = *(const uint2*)(tpk + a + 1024);  // c4+1 block
            bf[ti] = b.v;
        }
#pragma unroll
        for (int mi = 0; mi < 4; ++mi)
#pragma unroll
            for (int ti = 0; ti < 4; ++ti)
                accS[mi][ti] = MFMA(af[mi], bf[ti], accS[mi][ti]);
    }
    // add per-column offset v[m] (the only bias term that survives softmax)
#pragma unroll
    for (int mi = 0; mi < 4; ++mi)
#pragma unroll
        for (int ti = 0; ti < 4; ++ti)
#pragma unroll
            for (int r = 0; r < 4; ++r)
                accS[mi][ti][r] += vm[ti];

    // row max
    float pm[4][4];
#pragma unroll
    for (int mi = 0; mi < 4; ++mi)
#pragma unroll
        for (int r = 0; r < 4; ++r) {
            float m = fmaxf(fmaxf(accS[mi][0][r], accS[mi][1][r]),
                            fmaxf(accS[mi][2][r], accS[mi][3][r]));
#pragma unroll
            for (int d = 1; d < 16; d <<= 1) m = fmaxf(m, __shfl_xor(m, d, 64));
            pm[mi][r] = m;
        }
    if (l15 == 0) {
#pragma unroll
        for (int mi = 0; mi < 4; ++mi)
#pragma unroll
            for (int r = 0; r < 4; ++r) sRed[wave][mi * 16 + qd * 4 + r] = pm[mi][r];
    }
    __syncthreads();
    if (tid < 64)
        sMax[tid] = fmaxf(fmaxf(sRed[0][tid], sRed[1][tid]), fmaxf(sRed[2][tid], sRed[3][tid]));
    __syncthreads();

    // exp + row sum; pack P to f16 early to cut VGPR pressure
    union PK { f16 h[4]; uint2 u; };
    PK pH[4][4];
    float ps[4][4];
#pragma unroll
    for (int mi = 0; mi < 4; ++mi)
#pragma unroll
        for (int r = 0; r < 4; ++r) {
            const float M = sMax[mi * 16 + qd * 4 + r];
            float s = 0.f;
#pragma unroll
            for (int ti = 0; ti < 4; ++ti) {
                float e = __expf(accS[mi][ti][r] - M);
                pH[mi][ti].h[r] = (f16)e;
                s += e;
            }
#pragma unroll
            for (int d = 1; d < 16; d <<= 1) s += __shfl_xor(s, d, 64);
            ps[mi][r] = s;
        }
    if (l15 == 0) {
#pragma unroll
        for (int mi = 0; mi < 4; ++mi)
#pragma unroll
            for (int r = 0; r < 4; ++r) sRed[wave][mi * 16 + qd * 4 + r] = ps[mi][r];
    }
    __syncthreads();
    if (tid < 64) sSum[tid] = sRed[0][tid] + sRed[1][tid] + sRed[2][tid] + sRed[3][tid];

    // ---- phase O: Y^T[n][c] = sum_m P[n,m] xh[c,m], 4 chunks of 64 cols
    f32x4 accO[4][3] = {};  // [tn][tc]
#pragma unroll
    for (int h = 0; h < 4; ++h) {
        if (wave == h) {   // chunk h's cols live in wave h's accumulator
#pragma unroll
            for (int mi = 0; mi < 4; ++mi)
#pragma unroll
                for (int ti = 0; ti < 4; ++ti)
#pragma unroll
                    for (int r = 0; r < 4; ++r)
                        sP[(mi * 16 + qd * 4 + r) * SPS + ti * 16 + l15] = pH[mi][ti].h[r];
        }
        __syncthreads();
#pragma unroll
        for (int k = 0; k < 2; ++k) {
            const int ml = k * 32 + qd * 8;        // local col in chunk
            const int m0 = h * 64 + ml;            // global m
            f16x8 af[4], bf[3];
#pragma unroll
            for (int tn = 0; tn < 4; ++tn)
                af[tn] = *(const f16x8*)(sP + (tn * 16 + l15) * SPS + ml);
#pragma unroll
            for (int tc = 0; tc < 3; ++tc)
                bf[tc] = *(const f16x8*)(xh + ((size_t)win * C + wave * 48 + tc * 16 + l15) * 256 + m0);
#pragma unroll
            for (int tn = 0; tn < 4; ++tn)
#pragma unroll
                for (int tc = 0; tc < 3; ++tc)
                    accO[tn][tc] = MFMA(af[tn], bf[tc], accO[tn][tc]);
        }
        if (h < 3) __syncthreads();  // protect sP before next chunk's overwrite
    }

    // write scaled O^T to sOT (aliases sQ; sQ reads all done in phase S)
    f16* sOT = sQ;
#pragma unroll
    for (int tn = 0; tn < 4; ++tn)
#pragma unroll
        for (int r = 0; r < 4; ++r) {
            const int n = tn * 16 + qd * 4 + r;
            const float rs = 1.0f / sSum[n];
#pragma unroll
            for (int tc = 0; tc < 3; ++tc)
                sOT[n * SQS + wave * 48 + tc * 16 + l15] = (f16)(accO[tn][tc][r] * rs);
        }
    __syncthreads();

    // ---- phase proj: out[o][n] = Wo[o][:]·Y[:,n] + b2[o] + x ; wave -> 48 o-rows
    f32x4 accP[3][4] = {};  // [to][tn]
#pragma unroll
    for (int k = 0; k < 6; ++k) {
        const int c0 = k * 32 + qd * 8;
        f16x8 af[3], bf[4];
#pragma unroll
        for (int to = 0; to < 3; ++to)
            af[to] = *(const f16x8*)(Wo + (wave * 48 + to * 16 + l15) * C + c0);
#pragma unroll
        for (int tn = 0; tn < 4; ++tn)
            bf[tn] = *(const f16x8*)(sOT + (tn * 16 + l15) * SQS + c0);
#pragma unroll
        for (int to = 0; to < 3; ++to)
#pragma unroll
            for (int tn = 0; tn < 4; ++tn)
                accP[to][tn] = MFMA(af[to], bf[tn], accP[to][tn]);
    }
    // epilogue: D[row=o][col=n]; h = wh*16 + rblk*4 + tn, w = ww*16 + l15
#pragma unroll
    for (int to = 0; to < 3; ++to)
#pragma unroll
        for (int r = 0; r < 4; ++r) {
            const int o = wave * 48 + to * 16 + qd * 4 + r;
            const float pb = b2[o];
#pragma unroll
            for (int tn = 0; tn < 4; ++tn) {
                const size_t idx = (((size_t)(batch * C + o) * 256) + wh * 16 + rblk * 4 + tn) * 256 + ww * 16 + l15;
                out[idx] = accP[to][tn][r] + pb + x[idx];
            }
        }
}

// ---------------- launch ----------------
extern "C" void kernel_launch(void* const* d_in, const int* in_sizes, int n_in,
                              void* d_out, int out_size, void* d_ws, size_t ws_size,
                              hipStream_t stream) {
    const float* x      = (const float*)d_in[0];
    const float* qkv_w  = (const float*)d_in[1];
    const float* qkv_b  = (const float*)d_in[2];
    const float* proj_w = (const float*)d_in[3];
    const float* proj_b = (const float*)d_in[4];
    float* out = (float*)d_out;

    char* ws = (char*)d_ws;
    const size_t TPK_BYTES = (size_t)1024 * 49 * 256 * 4 * 2;  // 102,760,448
    const size_t XH_BYTES  = (size_t)1024 * 192 * 256 * 2;     // 100,663,296
    const size_t MH_BYTES  = (size_t)256 * 192 * 2;            // 98,304 (zero-padded rows)
    const size_t WO_BYTES  = (size_t)192 * 192 * 2;            // 73,728
    f16*   tpk = (f16*)(ws);
    f16*   xh  = (f16*)(ws + TPK_BYTES);
    f16*   Mh  = (f16*)(ws + TPK_BYTES + XH_BYTES);
    f16*   Wo  = (f16*)(ws + TPK_BYTES + XH_BYTES + MH_BYTES);
    float* b2  = (float*)(ws + TPK_BYTES + XH_BYTES + MH_BYTES + WO_BYTES);

    prep_kernel<<<337, 256, 0, stream>>>(qkv_w, qkv_b, proj_w, proj_b, Mh, Wo, b2);
    xt_kernel<<<4096, 256, 0, stream>>>(x, Mh, tpk, xh);
    attn_kernel<<<4096, 256, 0, stream>>>(x, tpk, xh, Wo, b2, out);
}

// Round 2
// 649.556 us; speedup vs baseline: 1.2172x; 1.2172x over previous
//
#include <hip/hip_runtime.h>
#include <stdint.h>

typedef _Float16 f16;
typedef __attribute__((ext_vector_type(8))) _Float16 f16x8;
typedef __attribute__((ext_vector_type(4))) float f32x4;

#define MFMA(a, b, c) __builtin_amdgcn_mfma_f32_16x16x32_f16((a), (b), (c), 0, 0, 0)

static constexpr int C = 192;     // channels
// Algebraic folding (softmax is row-shift-invariant):
//   S = softmax(x^T M x + v[m]),  M = Wq^T Wk (192x192), v = (Wk^T qb)^T x
//   out = Wo (x P^T) + b2 + x,    Wo = Wp Wv, b2 = Wp vb + pb
// t = M' x  with M' rows 0..191 = M, row 192 = Wk^T qb (gives v[m])
// tpk: [win][c4 (48)][tok 256][4] f16 (packed like old Kp)
// vmg: [win][tok] f16 (row 192 of t)
// xq : [win][c4 (48)][tok 256][4] f16 (x itself, packed — attn staging operand)
// xh : [win][c (192)][tok 256] f16 (x itself, channel-major — attn V operand)

union U8x { uint2 u2[2]; f16x8 v; };

// ---------------- kernel 0: fold weights ----------------
__global__ __launch_bounds__(256)
void prep_kernel(const float* __restrict__ qkv_w, const float* __restrict__ qkv_b,
                 const float* __restrict__ proj_w, const float* __restrict__ proj_b,
                 f16* __restrict__ Mh, f16* __restrict__ Wo, float* __restrict__ b2) {
    const int idx = blockIdx.x * 256 + threadIdx.x;
    if (idx < 256 * 192) {
        const int r = idx / 192, c = idx % 192;
        float s = 0.f;
        if (r < 192) {
#pragma unroll 4
            for (int o = 0; o < 192; ++o)
                s += qkv_w[o * 192 + r] * qkv_w[(192 + o) * 192 + c];   // Wq[o,r]*Wk[o,c]
        } else if (r == 192) {
#pragma unroll 4
            for (int o = 0; o < 192; ++o)
                s += qkv_b[o] * qkv_w[(192 + o) * 192 + c];             // qb[o]*Wk[o,c]
        }
        Mh[idx] = (f16)s;
    } else if (idx < 256 * 192 + 192 * 192) {
        const int j = idx - 256 * 192;
        const int r = j / 192, c = j % 192;
        float s = 0.f;
#pragma unroll 4
        for (int c2 = 0; c2 < 192; ++c2)
            s += proj_w[r * 192 + c2] * qkv_w[(384 + c2) * 192 + c];    // Wp[r,c2]*Wv[c2,c]
        Wo[j] = (f16)s;
    } else if (idx < 256 * 192 + 192 * 192 + 192) {
        const int o = idx - (256 * 192 + 192 * 192);
        float s = proj_b[o];
        for (int c2 = 0; c2 < 192; ++c2)
            s += proj_w[o * 192 + c2] * qkv_b[384 + c2];                // Wp[o,c2]*vb[c2]
        b2[o] = s;
    }
}

// ---------------- kernel 1: t = M' x  (+ packed/ch-major f16 copies of x) ----------------
// grid: 4096 = 1024 windows * 4 token-blocks ; block: 256 threads (4 waves)
#define XS 200  // LDS row stride (f16): 16B-aligned rows
__global__ __launch_bounds__(256, 4)
void xt_kernel(const float* __restrict__ x, const f16* __restrict__ Mh,
               f16* __restrict__ tpk, f16* __restrict__ vmg,
               f16* __restrict__ xq, f16* __restrict__ xh) {
    __shared__ f16 xs[64 * XS];  // [token_local][c]
    const int tid = threadIdx.x;
    const int wg = blockIdx.x;
    const int win = wg >> 2, tb = wg & 3;
    const int batch = win >> 8, wh = (win >> 4) & 15, ww = win & 15;
    const int i0 = tb * 4;  // first window-row of this 64-token block

    // stage x tile -> xs[token][c] (f16), coalesced float4 reads
    for (int e = 0; e < 12; ++e) {
        int f = e * 1024 + tid * 4;      // covers c*64 + nl, 12288 elements
        int c = f >> 6, nl = f & 63;
        int i = nl >> 4, j = nl & 15;    // j in {0,4,8,12}
        const float4 v4 = *(const float4*)(x + (((size_t)(batch * C + c) * 256 + (wh * 16 + i0 + i)) * 256 + ww * 16 + j));
        xs[(nl + 0) * XS + c] = (f16)v4.x;
        xs[(nl + 1) * XS + c] = (f16)v4.y;
        xs[(nl + 2) * XS + c] = (f16)v4.z;
        xs[(nl + 3) * XS + c] = (f16)v4.w;
    }
    __syncthreads();

    // xq: packed-c4 copy of x (coalesced 8B stores) — goes out early, overlaps MFMA
    for (int it = 0; it < 12; ++it) {
        int e = it * 256 + tid;          // 3072 = 48 c4 * 64 n
        int n = e & 63, c4 = e >> 6;
        *(uint2*)(xq + (((size_t)win * 48 + c4) * 256 + tb * 64 + n) * 4) =
            *(const uint2*)(xs + n * XS + c4 * 4);
    }
    // xh: channel-major copy of x (coalesced 8B stores)
    for (int it = 0; it < 12; ++it) {
        int e = it * 256 + tid;          // 3072 = 192 c * 16 tok-groups
        int c = e >> 4, t4 = (e & 15) * 4;
        union { f16 h[4]; uint2 u; } pk;
        pk.h[0] = xs[(t4 + 0) * XS + c];
        pk.h[1] = xs[(t4 + 1) * XS + c];
        pk.h[2] = xs[(t4 + 2) * XS + c];
        pk.h[3] = xs[(t4 + 3) * XS + c];
        *(uint2*)(xh + ((size_t)win * C + c) * 256 + tb * 64 + t4) = pk.u;
    }

    const int wave = tid >> 6, lane = tid & 63, l15 = lane & 15, qd = lane >> 4;
    // wave w owns t-rows [64w, 64w+64) (208 real rows; Mh zero-padded above)
    const int rb = wave;
    const int nmi = (wave == 3) ? 1 : 4;   // wave 3 only needs rows 192..207
    f32x4 acc[4][4] = {};  // [mi][ti]
#pragma unroll
    for (int k = 0; k < 6; ++k) {
        const int c0 = k * 32 + qd * 8;
        f16x8 af[4], bf[4];
#pragma unroll
        for (int mi = 0; mi < 4; ++mi)
            if (mi < nmi)
                af[mi] = *(const f16x8*)(Mh + (rb * 64 + mi * 16 + l15) * C + c0);
#pragma unroll
        for (int ti = 0; ti < 4; ++ti)
            bf[ti] = *(const f16x8*)(xs + (ti * 16 + l15) * XS + c0);
#pragma unroll
        for (int mi = 0; mi < 4; ++mi)
            if (mi < nmi)
#pragma unroll
                for (int ti = 0; ti < 4; ++ti)
                    acc[mi][ti] = MFMA(af[mi], bf[ti], acc[mi][ti]);
    }
    // epilogue
    if (rb < 3) {  // t rows 0..191 -> tpk packed (coalesced 8B)
#pragma unroll
        for (int mi = 0; mi < 4; ++mi) {
            const int c4 = rb * 16 + mi * 4 + qd;
#pragma unroll
            for (int ti = 0; ti < 4; ++ti) {
                const int tok = tb * 64 + ti * 16 + l15;
                union { f16 h[4]; uint2 u; } pk;
                pk.h[0] = (f16)acc[mi][ti][0];
                pk.h[1] = (f16)acc[mi][ti][1];
                pk.h[2] = (f16)acc[mi][ti][2];
                pk.h[3] = (f16)acc[mi][ti][3];
                *(uint2*)(tpk + (((size_t)win * 48 + c4) * 256 + tok) * 4) = pk.u;
            }
        }
    } else if (qd == 0) {  // t row 192 (= v[m]) -> vmg
#pragma unroll
        for (int ti = 0; ti < 4; ++ti)
            vmg[(size_t)win * 256 + tb * 64 + ti * 16 + l15] = (f16)acc[0][ti][0];
    }
}

// ---------------- kernel 2: fused attention + proj + residual ----------------
// grid: 4096 ; block: 256 threads (4 waves). XCD swizzle: 4 WGs of one window -> same XCD.
#define SQS 200  // sQ / sOT row stride (f16)
#define SPS 136  // sP row stride (f16), holds one 128-col chunk
__global__ __launch_bounds__(256, 3)
void attn_kernel(const f16* __restrict__ xq, const f16* __restrict__ tpk,
                 const f16* __restrict__ vmg, const f16* __restrict__ xh,
                 const f16* __restrict__ Wo, const float* __restrict__ b2,
                 const float* __restrict__ x, float* __restrict__ out) {
    __shared__ f16 sQ[64 * SQS];   // x rows [n][c]; later reused as sOT [n][c]
    __shared__ f16 sP[64 * SPS];   // softmaxed scores, one 128-col chunk
    __shared__ float sRed[4][64];
    __shared__ float sMax[64];
    __shared__ float sSum[64];

    const int tid = threadIdx.x;
    const int wg = blockIdx.x;
    const int win = ((wg >> 5) << 3) | (wg & 7);
    const int rblk = (wg >> 3) & 3;
    const int n0 = rblk * 64;
    const int batch = win >> 8, wh = (win >> 4) & 15, ww = win & 15;
    const int wave = tid >> 6, lane = tid & 63, l15 = lane & 15, qd = lane >> 4;

    // stage 64 x-rows -> sQ from packed layout (coalesced 8B reads)
    for (int it = 0; it < 12; ++it) {
        int ch = it * 256 + tid;              // 3072 = 64 n * 48 c4
        int n = ch & 63, c4 = ch >> 6;
        *(uint2*)(sQ + n * SQS + c4 * 4) =
            *(const uint2*)(xq + (((size_t)win * 48 + c4) * 256 + n0 + n) * 4);
    }
    // v[m] column offsets — issue loads early
    float vm[4];
#pragma unroll
    for (int ti = 0; ti < 4; ++ti)
        vm[ti] = (float)vmg[(size_t)win * 256 + wave * 64 + ti * 16 + l15];
    __syncthreads();

    // ---- phase S: A[n][m] = x^T t ; wave -> 64-col block
    f32x4 accS[4][4] = {};  // [mi: row subtile][ti: col subtile]
#pragma unroll
    for (int k = 0; k < 6; ++k) {
        const int c0 = k * 32 + qd * 8;
        const int c4 = c0 >> 2;
        f16x8 af[4], bf[4];
#pragma unroll
        for (int mi = 0; mi < 4; ++mi)
            af[mi] = *(const f16x8*)(sQ + (mi * 16 + l15) * SQS + c0);
#pragma unroll
        for (int ti = 0; ti < 4; ++ti) {
            const int m = wave * 64 + ti * 16 + l15;
            const size_t a = (((size_t)win * 48 + c4) * 256 + m) * 4;
            U8x b;
            b.u2[0] = *(const uint2*)(tpk + a);
            b.u2[1] = *(const uint2*)(tpk + a + 1024);  // c4+1 block
            bf[ti] = b.v;
        }
#pragma unroll
        for (int mi = 0; mi < 4; ++mi)
#pragma unroll
            for (int ti = 0; ti < 4; ++ti)
                accS[mi][ti] = MFMA(af[mi], bf[ti], accS[mi][ti]);
    }
    // add per-column offset v[m] (the only bias term that survives softmax)
#pragma unroll
    for (int mi = 0; mi < 4; ++mi)
#pragma unroll
        for (int ti = 0; ti < 4; ++ti)
#pragma unroll
            for (int r = 0; r < 4; ++r)
                accS[mi][ti][r] += vm[ti];

    // row max
    float pm[4][4];
#pragma unroll
    for (int mi = 0; mi < 4; ++mi)
#pragma unroll
        for (int r = 0; r < 4; ++r) {
            float m = fmaxf(fmaxf(accS[mi][0][r], accS[mi][1][r]),
                            fmaxf(accS[mi][2][r], accS[mi][3][r]));
#pragma unroll
            for (int d = 1; d < 16; d <<= 1) m = fmaxf(m, __shfl_xor(m, d, 64));
            pm[mi][r] = m;
        }
    if (l15 == 0) {
#pragma unroll
        for (int mi = 0; mi < 4; ++mi)
#pragma unroll
            for (int r = 0; r < 4; ++r) sRed[wave][mi * 16 + qd * 4 + r] = pm[mi][r];
    }
    __syncthreads();
    if (tid < 64)
        sMax[tid] = fmaxf(fmaxf(sRed[0][tid], sRed[1][tid]), fmaxf(sRed[2][tid], sRed[3][tid]));
    __syncthreads();

    // exp + row sum; pack P to f16 early to cut VGPR pressure
    union PK { f16 h[4]; uint2 u; };
    PK pH[4][4];
    float ps[4][4];
#pragma unroll
    for (int mi = 0; mi < 4; ++mi)
#pragma unroll
        for (int r = 0; r < 4; ++r) {
            const float M = sMax[mi * 16 + qd * 4 + r];
            float s = 0.f;
#pragma unroll
            for (int ti = 0; ti < 4; ++ti) {
                float e = __expf(accS[mi][ti][r] - M);
                pH[mi][ti].h[r] = (f16)e;
                s += e;
            }
#pragma unroll
            for (int d = 1; d < 16; d <<= 1) s += __shfl_xor(s, d, 64);
            ps[mi][r] = s;
        }
    if (l15 == 0) {
#pragma unroll
        for (int mi = 0; mi < 4; ++mi)
#pragma unroll
            for (int r = 0; r < 4; ++r) sRed[wave][mi * 16 + qd * 4 + r] = ps[mi][r];
    }
    __syncthreads();
    if (tid < 64) sSum[tid] = sRed[0][tid] + sRed[1][tid] + sRed[2][tid] + sRed[3][tid];

    // ---- phase O: Y^T[n][c] = sum_m P[n,m] xh[c,m], two 128-col chunks
    f32x4 accO[4][3] = {};  // [tn][tc]
#pragma unroll
    for (int h = 0; h < 2; ++h) {
        if ((wave >> 1) == h) {
            const int cl = (wave & 1) * 64;
#pragma unroll
            for (int mi = 0; mi < 4; ++mi)
#pragma unroll
                for (int ti = 0; ti < 4; ++ti)
#pragma unroll
                    for (int r = 0; r < 4; ++r)
                        sP[(mi * 16 + qd * 4 + r) * SPS + cl + ti * 16 + l15] = pH[mi][ti].h[r];
        }
        __syncthreads();
#pragma unroll
        for (int k = 0; k < 4; ++k) {
            const int ml = k * 32 + qd * 8;        // local col in chunk
            const int m0 = h * 128 + ml;           // global m
            f16x8 af[4], bf[3];
#pragma unroll
            for (int tn = 0; tn < 4; ++tn)
                af[tn] = *(const f16x8*)(sP + (tn * 16 + l15) * SPS + ml);
#pragma unroll
            for (int tc = 0; tc < 3; ++tc)
                bf[tc] = *(const f16x8*)(xh + ((size_t)win * C + wave * 48 + tc * 16 + l15) * 256 + m0);
#pragma unroll
            for (int tn = 0; tn < 4; ++tn)
#pragma unroll
                for (int tc = 0; tc < 3; ++tc)
                    accO[tn][tc] = MFMA(af[tn], bf[tc], accO[tn][tc]);
        }
        if (h == 0) __syncthreads();  // protect sP before chunk-1 overwrite
    }

    // prefetch residual x for the epilogue (covered by sOT round-trip + proj MFMAs)
    float xres[3][4][4];
#pragma unroll
    for (int to = 0; to < 3; ++to)
#pragma unroll
        for (int r = 0; r < 4; ++r) {
            const int o = wave * 48 + to * 16 + qd * 4 + r;
#pragma unroll
            for (int tn = 0; tn < 4; ++tn) {
                const size_t idx = (((size_t)(batch * C + o) * 256) + wh * 16 + rblk * 4 + tn) * 256 + ww * 16 + l15;
                xres[to][r][tn] = x[idx];
            }
        }

    // write scaled O^T to sOT (aliases sQ; sQ reads all done in phase S)
    f16* sOT = sQ;
#pragma unroll
    for (int tn = 0; tn < 4; ++tn)
#pragma unroll
        for (int r = 0; r < 4; ++r) {
            const int n = tn * 16 + qd * 4 + r;
            const float rs = 1.0f / sSum[n];
#pragma unroll
            for (int tc = 0; tc < 3; ++tc)
                sOT[n * SQS + wave * 48 + tc * 16 + l15] = (f16)(accO[tn][tc][r] * rs);
        }
    __syncthreads();

    // ---- phase proj: out[o][n] = Wo[o][:]·Y[:,n] + b2[o] + x ; wave -> 48 o-rows
    f32x4 accP[3][4] = {};  // [to][tn]
#pragma unroll
    for (int k = 0; k < 6; ++k) {
        const int c0 = k * 32 + qd * 8;
        f16x8 af[3], bf[4];
#pragma unroll
        for (int to = 0; to < 3; ++to)
            af[to] = *(const f16x8*)(Wo + (wave * 48 + to * 16 + l15) * C + c0);
#pragma unroll
        for (int tn = 0; tn < 4; ++tn)
            bf[tn] = *(const f16x8*)(sOT + (tn * 16 + l15) * SQS + c0);
#pragma unroll
        for (int to = 0; to < 3; ++to)
#pragma unroll
            for (int tn = 0; tn < 4; ++tn)
                accP[to][tn] = MFMA(af[to], bf[tn], accP[to][tn]);
    }
    // epilogue: D[row=o][col=n]; h = wh*16 + rblk*4 + tn, w = ww*16 + l15
#pragma unroll
    for (int to = 0; to < 3; ++to)
#pragma unroll
        for (int r = 0; r < 4; ++r) {
            const int o = wave * 48 + to * 16 + qd * 4 + r;
            const float pb = b2[o];
#pragma unroll
            for (int tn = 0; tn < 4; ++tn) {
                const size_t idx = (((size_t)(batch * C + o) * 256) + wh * 16 + rblk * 4 + tn) * 256 + ww * 16 + l15;
                out[idx] = accP[to][tn][r] + pb + xres[to][r][tn];
            }
        }
}

// ---------------- launch ----------------
extern "C" void kernel_launch(void* const* d_in, const int* in_sizes, int n_in,
                              void* d_out, int out_size, void* d_ws, size_t ws_size,
                              hipStream_t stream) {
    const float* x      = (const float*)d_in[0];
    const float* qkv_w  = (const float*)d_in[1];
    const float* qkv_b  = (const float*)d_in[2];
    const float* proj_w = (const float*)d_in[3];
    const float* proj_b = (const float*)d_in[4];
    float* out = (float*)d_out;

    char* ws = (char*)d_ws;
    const size_t PK_BYTES  = (size_t)1024 * 48 * 256 * 4 * 2;  // 100,663,296
    const size_t VMG_BYTES = (size_t)1024 * 256 * 2;           // 524,288
    f16*   tpk = (f16*)(ws);
    f16*   xq  = (f16*)(ws + PK_BYTES);
    f16*   xh  = (f16*)(ws + 2 * PK_BYTES);
    f16*   vmg = (f16*)(ws + 3 * PK_BYTES);
    f16*   Mh  = (f16*)(ws + 3 * PK_BYTES + VMG_BYTES);
    f16*   Wo  = (f16*)(ws + 3 * PK_BYTES + VMG_BYTES + 256 * 192 * 2);
    float* b2  = (float*)(ws + 3 * PK_BYTES + VMG_BYTES + 256 * 192 * 2 + 192 * 192 * 2);

    prep_kernel<<<337, 256, 0, stream>>>(qkv_w, qkv_b, proj_w, proj_b, Mh, Wo, b2);
    xt_kernel<<<4096, 256, 0, stream>>>(x, Mh, tpk, vmg, xq, xh);
    attn_kernel<<<4096, 256, 0, stream>>>(xq, tpk, vmg, xh, Wo, b2, x, out);
}